// Round 1
// baseline (536.809 us; speedup 1.0000x reference)
//
#include <hip/hip_runtime.h>

// ShapeContext: weight is eye(NOUT) by construction (identity sparse-conv),
// so out[n, k*NIN + i] = (rules[k,n] < N ? features[rules[k,n], i] : 0) + bias[k*NIN+i].
// Pure gather -> memory-bound.
//
// R4: n-major work mapping. Previous kernel was k-major: each wave wrote
// 8 x 128B chunks at stride 3456B, sweeping the 453MB output as strided
// 128B islands -> DRAM row-buffer thrash (~0.9 TB/s effective). Here
// tid -> (n, j) with j = k*8 + c, so the nontemporal store stream is
// out_f4[tid]: perfectly linear, same pattern that lets the harness fills
// hit 6.3 TB/s on this very buffer.
//
// rules: read by 8 same-address lanes (wave broadcast, one L2 request);
// each 64B line is reused by adjacent blocks -> plain cached load now
// (the old nontemporal hint would defeat that reuse).
// features: per wave 8 random 128B rows (8 lanes x 16B coalesced each);
// 16.8MB working set is LLC-resident, demand served from cache.

#define N_SITES 131072   // 2^17
#define NIN 32
#define FV 27
#define NOUT 864         // FV * NIN
#define F4_PER_SITE 216  // NOUT / 4
#define TOTAL_F4 (N_SITES * (long long)F4_PER_SITE)  // 28,311,552

typedef float f32x4 __attribute__((ext_vector_type(4)));

__global__ __launch_bounds__(256) void shape_context_gather(
    const float* __restrict__ features,   // [N, NIN]
    const float* __restrict__ bias,       // [NOUT]
    const int*   __restrict__ rules,      // [FV, N]
    float*       __restrict__ out)        // [N, NOUT]
{
    unsigned tid = blockIdx.x * 256u + threadIdx.x;
    if (tid >= (unsigned)TOTAL_F4) return;      // grid divides exactly; safety

    unsigned n = tid / F4_PER_SITE;             // site (magic-mul division)
    unsigned j = tid - n * F4_PER_SITE;         // 0..215 within site
    unsigned k = j >> 3;                        // filter offset 0..26
    unsigned c = j & 7;                         // float4 within 32-ch row

    int r = rules[k * (unsigned)N_SITES + n];   // cached; 8 lanes broadcast

    bool valid = (unsigned)r < (unsigned)N_SITES;
    unsigned rr = valid ? (unsigned)r : 0u;     // branch-free clamp+mask
    f32x4 v = ((const f32x4*)features)[rr * 8u + c];
    if (!valid) v = (f32x4){0.f, 0.f, 0.f, 0.f};

    v += ((const f32x4*)bias)[j];               // 3.4KB, L1-resident

    __builtin_nontemporal_store(v, ((f32x4*)out) + tid);  // linear stream
}

extern "C" void kernel_launch(void* const* d_in, const int* in_sizes, int n_in,
                              void* d_out, int out_size, void* d_ws, size_t ws_size,
                              hipStream_t stream) {
    const float* features = (const float*)d_in[0];
    // d_in[1] = weight: eye(NOUT) by ShapeContext construction -> gather, not matmul
    const float* bias     = (const float*)d_in[2];
    const int*   rules    = (const int*)d_in[3];
    float*       out      = (float*)d_out;

    const long long total   = TOTAL_F4;
    const int       threads = 256;
    const int       blocks  = (int)((total + threads - 1) / threads);

    shape_context_gather<<<blocks, threads, 0, stream>>>(features, bias, rules, out);
}